// Round 12
// baseline (297.393 us; speedup 1.0000x reference)
//
#include <hip/hip_runtime.h>
#include <math.h>

#define H 51
#define TSEEN 256
#define FUT 16
#define TTOT (TSEEN + FUT)
#define NB 8
#define THREADS 1024
#define NWAVE 16
#define NBLOCKS (2048 / NB)   // 256 blocks -> 1/CU, 16 waves = 4 waves/SIMD

typedef _Float16 f16;
typedef _Float16 f16x8 __attribute__((ext_vector_type(8)));
typedef float f32x4 __attribute__((ext_vector_type(4)));

__device__ __forceinline__ float fast_rcp(float x) { return __builtin_amdgcn_rcpf(x); }
// sigmoid/tanh via v_exp; both saturate cleanly (rcp(inf)=0)
__device__ __forceinline__ float sigf(float x) {
  return fast_rcp(1.f + __expf(-x));
}
__device__ __forceinline__ float tanhf_(float x) {
  return fmaf(2.f, fast_rcp(1.f + __expf(-2.f * x)), -1.f);
}

// lane^8 within each 16-lane row: DPP row_ror:8 (VALU pipe, not LDS!)
__device__ __forceinline__ float xor8f(float v) {
  return __int_as_float(__builtin_amdgcn_mov_dpp(__float_as_int(v), 0x128, 0xf, 0xf, true));
}

#define MFMA __builtin_amdgcn_mfma_f32_16x16x32_f16

__launch_bounds__(THREADS, 4)
__global__ void lstm2_kernel(const float* __restrict__ inp,
                             const float* __restrict__ Wih1,
                             const float* __restrict__ bih1,
                             const float* __restrict__ Whh1,
                             const float* __restrict__ bhh1,
                             const float* __restrict__ Wih2,
                             const float* __restrict__ bih2,
                             const float* __restrict__ Whh2,
                             const float* __restrict__ bhh2,
                             const float* __restrict__ Wlin,
                             const float* __restrict__ blin,
                             float* __restrict__ out)
{
  // B-operand buffers in MFMA fragment layout, hi/lo packed in COLUMNS:
  // col b (0..7) = h_hi of batch b, col b+8 = h_lo of batch b.
  // [parity][ktile][lane][j]; logical (k,n): lane = n + 16*((k&31)>>3), j = k&7
  __shared__ __align__(16) f16 Bh1[2][2][64][8];
  __shared__ __align__(16) f16 Bh2[2][2][64][8];
  __shared__ __align__(16) float xs[TSEEN][NB];
  __shared__ __align__(16) float parts[2][NB][NWAVE];
  __shared__ float outb[TTOT][NB];   // staged outputs; flushed once at the end

  const int tid  = threadIdx.x;
  const int wv   = tid >> 6;
  const int lane = tid & 63;
  const int l15  = lane & 15;
  const int g4   = lane >> 4;
  const int bq   = l15 & 7;            // this lane's batch for the cell phase
  const int baseb = blockIdx.x * NB;

  // balanced unit mapping: wave wv owns units [ubase, ubase+ucnt) (3 or 4)
  const int ubase = (51 * wv) >> 4;
  const int ucnt  = ((51 * (wv + 1)) >> 4) - ubase;

  // ---- zero B buffers (pad slots stay 0 forever) ----
  {
    f16* b1 = &Bh1[0][0][0][0];
    f16* b2 = &Bh2[0][0][0][0];
    for (int i = tid; i < 2 * 2 * 64 * 8; i += THREADS) {
      b1[i] = (f16)0.f; b2[i] = (f16)0.f;
    }
  }
  // ---- stage inputs (coalesced per batch row) ----
  for (int i = tid; i < NB * TSEEN; i += THREADS) {
    int b = i >> 8, t = i & 255;
    xs[t][b] = inp[(size_t)(baseb + b) * TSEEN + t];
  }
  if (tid < 2 * NB * NWAVE) (&parts[0][0][0])[tid] = 0.f;

  // ---- A fragments (f16), ONE M-tile/wave: virtual row v = 4*slot + gate ----
  // A layout: row = lane&15, k = 32*kt + 8*(lane>>4) + j
  f16x8 A1[2], A2[2], A3[2];
  {
    const int slotA = l15 >> 2;
    const int gA = l15 & 3;
    const bool vA = (slotA < ucnt);
    const int uA = ubase + (vA ? slotA : 0);
    const int row = gA * H + uA;
    #pragma unroll
    for (int kt = 0; kt < 2; ++kt) {
      #pragma unroll
      for (int j = 0; j < 8; ++j) {
        const int k = 32 * kt + 8 * g4 + j;
        float w1 = 0.f, w2 = 0.f, w3 = 0.f;
        if (vA) {
          if (k < H) {
            w1 = Whh1[row * H + k];
            w2 = Wih2[row * H + k];
            w3 = Whh2[row * H + k];
          } else if (k == H) {
            w1 = Wih1[row];        // x folded in as k-slot 51 (layer 1 only)
          }
        }
        A1[kt][j] = (f16)w1;
        A2[kt][j] = (f16)w2;
        A3[kt][j] = (f16)w3;
      }
    }
  }

  // ---- bias C-in fragments (C layout: unit-slot = g4, gate = reg) ----
  // Seed bias ONLY in hi columns (l15 < 8); lo columns accumulate from 0.
  f32x4 bias1, bias2;
  {
    const bool vb = (g4 < ucnt) && (l15 < 8);
    const int ucb = ubase + ((g4 < ucnt) ? g4 : 0);
    #pragma unroll
    for (int r = 0; r < 4; ++r) {
      const int rr = r * H + ucb;
      bias1[r] = vb ? (bih1[rr] + bhh1[rr]) : 0.f;
      bias2[r] = vb ? (bih2[rr] + bhh2[rr]) : 0.f;
    }
  }

  // ---- this lane's cell: unit ubase+g4, batch bq (hi lanes only) ----
  const bool vC = (g4 < ucnt) && (l15 < 8);
  const int uC = ubase + ((g4 < ucnt) ? g4 : 0);
  const float wl = vC ? Wlin[uC] : 0.f;
  const float bl = blin[0];
  const int wkt = uC >> 5;                    // h-frag write address for (uC,bq)
  const int wln = bq + 16 * ((uC >> 3) & 3);  // hi col; lo col = wln + 8
  const int wj  = uC & 7;

  float c1 = 0.f, c2 = 0.f;
  const f32x4 zf = {0.f, 0.f, 0.f, 0.f};

  __syncthreads();
  // x(0) into stale-parity h1 buffer, k-slot 51 (kt=1 -> lane n+32, j=3)
  if (tid < NB) {
    float x0 = xs[0][tid];
    f16 xh = (f16)x0;
    Bh1[1][1][tid + 32][3] = xh;                    // hi col
    Bh1[1][1][tid + 40][3] = (f16)(x0 - (float)xh); // lo col (+8)
  }
  __syncthreads();

  // ---- prologue: prefetch G1(0) from Bh1[pr=1] (h=0, x(0) at slot 51) ----
  f32x4 ac1;
  {
    const f16x8 p0 = *(const f16x8*)&Bh1[1][0][lane][0];
    const f16x8 p1 = *(const f16x8*)&Bh1[1][1][lane][0];
    f32x4 c = MFMA(A1[0], p0, bias1, 0, 0, 0);
    ac1 = MFMA(A1[1], p1, c, 0, 0, 0);
  }

  #pragma unroll 1
  for (int t = 0; t < TTOT; ++t) {
    const int pw = t & 1, pr = pw ^ 1;

    // ============ phase 1 (pure VALU): C1(t) from prefetched ac1 ============
    // recombine: q = a + xor8(a) (hi lane: hi + partner lo; no selects needed)
    float q0 = ac1[0] + xor8f(ac1[0]);
    float q1 = ac1[1] + xor8f(ac1[1]);
    float q2 = ac1[2] + xor8f(ac1[2]);
    float q3 = ac1[3] + xor8f(ac1[3]);
    {
      float iv = sigf(q0), fv = sigf(q1);
      float gv = tanhf_(q2), ov = sigf(q3);
      c1 = fmaf(fv, c1, iv * gv);
      float h1n = ov * tanhf_(c1);
      if (vC) {
        f16 hh = (f16)h1n;
        Bh1[pw][wkt][wln][wj]     = hh;
        Bh1[pw][wkt][wln + 8][wj] = (f16)(h1n - (float)hh);
      }
    }
    // x(t+1) from input, written pre-barrier (slot 51 disjoint from h-slots)
    if (t + 1 < TSEEN && tid < NB) {
      float xn = xs[t + 1][tid];
      f16 xh = (f16)xn;
      Bh1[pw][1][tid + 32][3] = xh;
      Bh1[pw][1][tid + 40][3] = (f16)(xn - (float)xh);
    }
    __syncthreads();   // barrier A — the only per-step barrier (seen phase)

    // deferred output: out(t-1) for t-1 in [0, 254] -> LDS stage
    if (t >= 1 && t < TSEEN && tid < NB) {
      const float4 pa = *(const float4*)&parts[pr][tid][0];
      const float4 pb = *(const float4*)&parts[pr][tid][4];
      const float4 pc = *(const float4*)&parts[pr][tid][8];
      const float4 pd = *(const float4*)&parts[pr][tid][12];
      float s = bl + (((pa.x + pa.y) + (pa.z + pa.w)) + ((pb.x + pb.y) + (pb.z + pb.w)))
                   + (((pc.x + pc.y) + (pc.z + pc.w)) + ((pd.x + pd.y) + (pd.z + pd.w)));
      outb[t - 1][tid] = s;
    }

    // ==== phase 2: G2(t) (hh + ih) AND prefetch G1(t+1) on shared frags ====
    const f16x8 b2k0 = *(const f16x8*)&Bh2[pr][0][lane][0];
    const f16x8 b2k1 = *(const f16x8*)&Bh2[pr][1][lane][0];
    const f16x8 f1k0 = *(const f16x8*)&Bh1[pw][0][lane][0];
    const f16x8 f1k1 = *(const f16x8*)&Bh1[pw][1][lane][0];

    f32x4 r1 = MFMA(A3[0], b2k0, bias2, 0, 0, 0);
    r1 = MFMA(A3[1], b2k1, r1, 0, 0, 0);
    f32x4 r2 = MFMA(A2[0], f1k0, zf, 0, 0, 0);
    r2 = MFMA(A2[1], f1k1, r2, 0, 0, 0);
    f32x4 ac2 = r1 + r2;
    // G1(t+1) prefetch: same B fragments, layer-1 A (x col live at slot 51)
    {
      f32x4 n = MFMA(A1[0], f1k0, bias1, 0, 0, 0);
      ac1 = MFMA(A1[1], f1k1, n, 0, 0, 0);
    }

    // recombine + cell + head
    q0 = ac2[0] + xor8f(ac2[0]);
    q1 = ac2[1] + xor8f(ac2[1]);
    q2 = ac2[2] + xor8f(ac2[2]);
    q3 = ac2[3] + xor8f(ac2[3]);
    float pv;
    {
      float iv = sigf(q0), fv = sigf(q1);
      float gv = tanhf_(q2), ov = sigf(q3);
      c2 = fmaf(fv, c2, iv * gv);
      float h2n = ov * tanhf_(c2);
      pv = wl * h2n;
      if (vC) {
        f16 hh = (f16)h2n;
        Bh2[pw][wkt][wln][wj]     = hh;
        Bh2[pw][wkt][wln + 8][wj] = (f16)(h2n - (float)hh);
      }
    }
    // head partial: sum over this wave's unit slots (g4 groups)
    pv += __shfl_xor(pv, 16, 64);
    pv += __shfl_xor(pv, 32, 64);
    if (lane < NB) parts[pw][lane][wv] = pv;

    // feedback phase: x(t+1) = out(t); redo G1(t+1) prefetch with fresh x
    if (t >= TSEEN - 1) {
      __syncthreads();   // publish parts[pw]
      if (tid < NB) {
        const float4 pa = *(const float4*)&parts[pw][tid][0];
        const float4 pb = *(const float4*)&parts[pw][tid][4];
        const float4 pc = *(const float4*)&parts[pw][tid][8];
        const float4 pd = *(const float4*)&parts[pw][tid][12];
        float fbv = bl + (((pa.x + pa.y) + (pa.z + pa.w)) + ((pb.x + pb.y) + (pb.z + pb.w)))
                       + (((pc.x + pc.y) + (pc.z + pc.w)) + ((pd.x + pd.y) + (pd.z + pd.w)));
        outb[t][tid] = fbv;
        if (t < TTOT - 1) {
          f16 xh = (f16)fbv;
          Bh1[pw][1][tid + 32][3] = xh;
          Bh1[pw][1][tid + 40][3] = (f16)(fbv - (float)xh);
        }
      }
      __syncthreads();   // slot-51 visible to all
      if (t < TTOT - 1) {
        const f16x8 g0 = *(const f16x8*)&Bh1[pw][0][lane][0];
        const f16x8 g1 = *(const f16x8*)&Bh1[pw][1][lane][0];
        f32x4 c = MFMA(A1[0], g0, bias1, 0, 0, 0);
        ac1 = MFMA(A1[1], g1, c, 0, 0, 0);
      }
    }
  }

  // ---- final flush: outb -> global (once) ----
  __syncthreads();
  for (int i = tid; i < TTOT * NB; i += THREADS) {
    int b = i / TTOT, t = i - b * TTOT;
    out[(size_t)(baseb + b) * TTOT + t] = outb[t][b];
  }
}

extern "C" void kernel_launch(void* const* d_in, const int* in_sizes, int n_in,
                              void* d_out, int out_size, void* d_ws, size_t ws_size,
                              hipStream_t stream) {
  (void)in_sizes; (void)n_in; (void)d_ws; (void)ws_size; (void)out_size;
  const float* inp  = (const float*)d_in[0];
  const float* Wih1 = (const float*)d_in[1];
  const float* bih1 = (const float*)d_in[2];
  const float* Whh1 = (const float*)d_in[3];
  const float* bhh1 = (const float*)d_in[4];
  const float* Wih2 = (const float*)d_in[5];
  const float* bih2 = (const float*)d_in[6];
  const float* Whh2 = (const float*)d_in[7];
  const float* bhh2 = (const float*)d_in[8];
  const float* Wlin = (const float*)d_in[9];
  const float* blin = (const float*)d_in[10];
  float* outp = (float*)d_out;

  lstm2_kernel<<<NBLOCKS, THREADS, 0, stream>>>(
      inp, Wih1, bih1, Whh1, bhh1, Wih2, bih2, Whh2, bhh2, Wlin, blin, outp);
}